// Round 7
// baseline (71.666 us; speedup 1.0000x reference)
//
#include <hip/hip_runtime.h>

// ConvCaps: b=16, A=32, B=32, K=3, P=4, stride=2, h=w=14 -> oh=ow=6
#define AA 32
#define BB 32
#define CC 16
#define KKA 288
#define OHW 6
#define LL 36
#define NBL 576
#define HH 14
#define WWD 14

// ---- workspace layout ----
// ushort region (from byte 0):
#define W1B_OFF   0ull          // bf16 [288][512][16]  (n, ch, c)
#define W2B_OFF   2359296ull    // bf16 [288][32][16]
#define PU16_OFF  2506752ull    // bf16 [288][576][16]  (n, bl, c)
#define AR16_OFF  5160960ull    // uint [288][16jp][576bl] (bf16 j-pair packed)
// float region starts at byte 20,938,752:
#define FREG_BYTE 20938752ull
#define AU_F      0ull          // f32 [576][288]        = 165,888
#define ARSUMP_F  165888ull     // f32 [36][32 j][576 bl] = 663,552
#define PREP_F    829440ull     // f32 [4][512][576]     = 1,179,648

typedef __attribute__((ext_vector_type(8))) short bf16x8;
typedef __attribute__((ext_vector_type(4))) float f32x4;
typedef __attribute__((ext_vector_type(16))) float f32x16;

__device__ __forceinline__ unsigned cvtpk(float lo, float hi) {
    unsigned r;
    asm("v_cvt_pk_bf16_f32 %0, %1, %2" : "=v"(r) : "v"(lo), "v"(hi));
    return r;
}
__device__ __forceinline__ float blo(unsigned u) {
    return __builtin_bit_cast(float, u << 16);
}
__device__ __forceinline__ float bhi(unsigned u) {
    return __builtin_bit_cast(float, u & 0xffff0000u);
}

// ---------------------------------------------------------------------------
// Kernel 0: fused weight-cvt (blocks 0..1223) + patch gather (blocks 1224..1735)
// pu16 written in [n][bl][c] order; auf in [bl][n].
// ---------------------------------------------------------------------------
__global__ __launch_bounds__(256) void k_prep(
    const float* __restrict__ W1, const float* __restrict__ W2,
    const float* __restrict__ a, const float* __restrict__ pose,
    unsigned short* __restrict__ W1b, unsigned short* __restrict__ W2b,
    unsigned short* __restrict__ pu16, float* __restrict__ auf)
{
    __shared__ float ps[16][196];
    __shared__ float as_[196];
    const int tid = threadIdx.x;

    if (blockIdx.x < 1224) {
        size_t i = ((size_t)blockIdx.x * 256 + tid) * 8;
        const float* src;
        unsigned short* dst;
        if (i < 2359296ull) { src = W1 + i; dst = W1b + i; }
        else { src = W2 + (i - 2359296ull); dst = W2b + (i - 2359296ull); }
        float4 v0 = *reinterpret_cast<const float4*>(src);
        float4 v1 = *reinterpret_cast<const float4*>(src + 4);
        uint4 o;
        o.x = cvtpk(v0.x, v0.y);
        o.y = cvtpk(v0.z, v0.w);
        o.z = cvtpk(v1.x, v1.y);
        o.w = cvtpk(v1.z, v1.w);
        *reinterpret_cast<uint4*>(dst) = o;
        return;
    }

    const int bid = blockIdx.x - 1224;
    const int b = bid >> 5, aidx = bid & 31;

    const float* psrc = pose + ((size_t)b * 512 + (size_t)aidx * 16) * 196;
    for (int t = tid; t < 3136; t += 256) ((float*)ps)[t] = psrc[t];
    const float* asrc = a + ((size_t)b * 32 + aidx) * 196;
    if (tid < 196) as_[tid] = asrc[tid];
    __syncthreads();

    for (int t = tid; t < 1296; t += 256) {
        int quad = t & 3;
        int l = (t >> 2) % 36;
        int kk = t / 144;
        int oy = l / 6, ox = l - (l / 6) * 6;
        int ki = kk / 3, kj = kk - (kk / 3) * 3;
        int pix = (oy * 2 + ki) * 14 + ox * 2 + kj;
        uint2 v;
        v.x = cvtpk(ps[quad * 4 + 0][pix], ps[quad * 4 + 1][pix]);
        v.y = cvtpk(ps[quad * 4 + 2][pix], ps[quad * 4 + 3][pix]);
        *reinterpret_cast<uint2*>(
            pu16 + (((size_t)(kk * 32 + aidx)) * 576 + b * 36 + l) * 16 + quad * 4) = v;
    }
    for (int t = tid; t < 324; t += 256) {
        int kk = t % 9, l = t / 9;
        int oy = l / 6, ox = l - (l / 6) * 6;
        int ki = kk / 3, kj = kk - (kk / 3) * 3;
        auf[((size_t)(b * 36 + l)) * KKA + kk * 32 + aidx] =
            as_[(oy * 2 + ki) * 14 + ox * 2 + kj];
    }
}

// ---------------------------------------------------------------------------
// Kernel 1: logits via DENSE 32x32x16 MFMA (one per n: 32 j x 32 bl), softmax
// in-register (no max-sub: |logit| <= ~3), aru + arsump partials out.
// Grid (18 bl-tiles of 32, 36 n-splits of 8); 4 waves x 2 n each.
// C layout: row j = (i&3)+8*(i>>2)+4*kg, col bl = lane&31 (HW-verified).
// (j,j+1) pairs are in-lane: jp(t) = (t&1) + 4*(t>>1) + 2*kg, t=0..7.
// ---------------------------------------------------------------------------
__global__ __launch_bounds__(256) void k_logit(
    const unsigned short* __restrict__ W2b, const unsigned short* __restrict__ pu16,
    const float* __restrict__ b2, const float* __restrict__ auf,
    unsigned* __restrict__ aru, float* __restrict__ arsump)
{
    __shared__ float b2_s[8][32];        // 1 KB
    __shared__ float au_s[8][32];        // 1 KB
    __shared__ float asum_s[4][64][16];  // 16 KB

    const int bl0 = blockIdx.x * 32;
    const int n0  = blockIdx.y * 8;
    const int tid = threadIdx.x;
    const int w = tid >> 6, lane = tid & 63;
    const int col = lane & 31, kg = lane >> 5;

    {
        int nl = tid >> 5, j = tid & 31;
        b2_s[nl][j] = b2[(size_t)(n0 + nl) * 32 + j];
        int nl2 = tid & 7, blr = tid >> 3;
        au_s[nl2][blr] = auf[((size_t)(bl0 + blr)) * KKA + n0 + nl2];
    }
    __syncthreads();

    float asum[16];
    #pragma unroll
    for (int i = 0; i < 16; ++i) asum[i] = 0.f;
    const f32x16 zv = {0.f,0.f,0.f,0.f,0.f,0.f,0.f,0.f,
                       0.f,0.f,0.f,0.f,0.f,0.f,0.f,0.f};

    #pragma unroll
    for (int nn = 0; nn < 2; ++nn) {
        const int nl = w * 2 + nn;
        const int n  = n0 + nl;
        uint4 a4 = *reinterpret_cast<const uint4*>(
            W2b + ((size_t)n * 32 + col) * 16 + kg * 8);
        uint4 b4 = *reinterpret_cast<const uint4*>(
            pu16 + ((size_t)n * 576 + bl0 + col) * 16 + kg * 8);
        f32x16 cd = __builtin_amdgcn_mfma_f32_32x32x16_bf16(
            __builtin_bit_cast(bf16x8, a4), __builtin_bit_cast(bf16x8, b4),
            zv, 0, 0, 0);

        // add bias, exp, row-sum
        float p[16];
        float s = 0.f;
        #pragma unroll
        for (int m = 0; m < 4; ++m) {
            float4 bb = *reinterpret_cast<const float4*>(&b2_s[nl][m * 8 + kg * 4]);
            p[m * 4 + 0] = __expf(cd[m * 4 + 0] + bb.x);
            p[m * 4 + 1] = __expf(cd[m * 4 + 1] + bb.y);
            p[m * 4 + 2] = __expf(cd[m * 4 + 2] + bb.z);
            p[m * 4 + 3] = __expf(cd[m * 4 + 3] + bb.w);
            s += p[m*4+0] + p[m*4+1] + p[m*4+2] + p[m*4+3];
        }
        s += __shfl_xor(s, 32);                  // add other kg half -> all 32 j
        const float scale = au_s[nl][col] / s;   // a_u * softmax
        #pragma unroll
        for (int i = 0; i < 16; ++i) { p[i] *= scale; asum[i] += p[i]; }

        // pack (j, j+1) pairs -> aru[n][jp][bl]
        #pragma unroll
        for (int t = 0; t < 8; ++t) {
            int jp = (t & 1) + 4 * (t >> 1) + 2 * kg;
            aru[((size_t)n * 16 + jp) * 576 + bl0 + col] =
                cvtpk(p[2 * t], p[2 * t + 1]);
        }
    }
    #pragma unroll
    for (int i = 0; i < 16; ++i) asum_s[w][lane][i] = asum[i];
    __syncthreads();
    // reduce 4 waves, write arsump[ns][j][bl] (coalesced 128B runs)
    #pragma unroll
    for (int k = 0; k < 4; ++k) {
        int idx = tid + k * 256;
        int L = idx & 63, i = idx >> 6;
        float s = asum_s[0][L][i] + asum_s[1][L][i]
                + asum_s[2][L][i] + asum_s[3][L][i];
        int row = (i & 3) + 8 * (i >> 2) + 4 * (L >> 5);
        arsump[((size_t)blockIdx.y * 32 + row) * 576 + bl0 + (L & 31)] = s;
    }
}

// ---------------------------------------------------------------------------
// Kernel 2: pose contraction via 32x32x16 MFMA, all-global operands.
// Grid 1152 = 18 bl-tiles(32) x 16 jp x 4 n-quarters(72), XCD-swizzled.
// inv(arsum) computed in-block (w==0) from the 36 arsump partials.
// ---------------------------------------------------------------------------
__global__ __launch_bounds__(256) void k_pose(
    const unsigned short* __restrict__ W1b, const unsigned short* __restrict__ pu16,
    const unsigned* __restrict__ aru, const float* __restrict__ arsump,
    float* __restrict__ prep)
{
    __shared__ float red_s[3][16][64];   // 12 KB

    const int bid = blockIdx.x;
    const int wg  = (bid & 7) * 144 + (bid >> 3);   // bijective (1152 % 8 == 0)
    const int q   = wg / 288;
    const int rem = wg - q * 288;
    const int jp  = rem / 18;
    const int bl0 = (rem - jp * 18) * 32;

    const int tid = threadIdx.x;
    const int w = tid >> 6, lane = tid & 63;
    const int col = lane & 31, kg = lane >> 5;

    // w==0 computes 1/arsum for its 2 j, 32 bl (72 coalesced loads)
    float ilo = 0.f, ihi = 0.f;
    if (w == 0) {
        #pragma unroll 9
        for (int r = 0; r < 36; ++r) {
            ilo += arsump[((size_t)r * 32 + jp * 2    ) * 576 + bl0 + col];
            ihi += arsump[((size_t)r * 32 + jp * 2 + 1) * 576 + bl0 + col];
        }
        ilo = 1.0f / ilo;
        ihi = 1.0f / ihi;
    }

    const unsigned short* wp = W1b + ((size_t)(jp * 32 + col)) * 16 + kg * 8;
    const unsigned short* pp = pu16 + ((size_t)(bl0 + col)) * 16 + kg * 8;
    const unsigned* ap = aru + (size_t)jp * 576 + bl0 + col;
    const int n0 = q * 72 + w * 18;

    float acc[16];
    #pragma unroll
    for (int i = 0; i < 16; ++i) acc[i] = 0.f;
    f32x16 zv = {0.f,0.f,0.f,0.f,0.f,0.f,0.f,0.f,0.f,0.f,0.f,0.f,0.f,0.f,0.f,0.f};

    #pragma unroll 6
    for (int i = 0; i < 18; ++i) {
        const size_t n = (size_t)(n0 + i);
        uint4 a4 = *reinterpret_cast<const uint4*>(wp + n * 8192);   // 512*16
        uint4 b4 = *reinterpret_cast<const uint4*>(pp + n * 9216);   // 576*16
        unsigned av = ap[n * 9216];                                  // 16*576
        f32x16 cd = __builtin_amdgcn_mfma_f32_32x32x16_bf16(
            __builtin_bit_cast(bf16x8, a4), __builtin_bit_cast(bf16x8, b4),
            zv, 0, 0, 0);
        float slo = blo(av), shi = bhi(av);
        #pragma unroll
        for (int r = 0; r < 8; ++r)  acc[r] = fmaf(cd[r], slo, acc[r]);
        #pragma unroll
        for (int r = 8; r < 16; ++r) acc[r] = fmaf(cd[r], shi, acc[r]);
    }

    if (w > 0) {
        #pragma unroll
        for (int i = 0; i < 16; ++i) red_s[w - 1][i][lane] = acc[i];
    }
    __syncthreads();
    if (w == 0) {
        #pragma unroll
        for (int i = 0; i < 16; ++i) {
            float v = acc[i] + red_s[0][i][lane] + red_s[1][i][lane] + red_s[2][i][lane];
            int r = (i & 3) + 8 * (i >> 2) + 4 * kg;       // C row
            float vv = v * (i < 8 ? ilo : ihi);
            prep[((size_t)q * 512 + jp * 32 + r) * NBL + bl0 + col] = vv;
        }
    }
}

// ---------------------------------------------------------------------------
// Kernel 3: blocks 0..127: BatchNorm (batch stats, biased var) + layout to
// [b, 512, 6, 6] (sums 4 n-quarter planes). Blocks 128..143: a_out.
// ---------------------------------------------------------------------------
__global__ __launch_bounds__(256) void k_bn(
    const float* __restrict__ prep, const float* __restrict__ gamma,
    const float* __restrict__ beta, const float* __restrict__ arsump,
    const float* __restrict__ auf, float* __restrict__ out_pose,
    float* __restrict__ out_a)
{
    __shared__ float atot_s[36];
    const int tid = threadIdx.x;
    const int wid = tid >> 6, lane = tid & 63;

    if (blockIdx.x < 128) {
        const int ch = blockIdx.x * 4 + wid;
        const float* p0 = prep + (size_t)ch * NBL;

        float sum = 0.f, sq = 0.f;
        float v[9];
        #pragma unroll
        for (int k = 0; k < 9; ++k) {
            int i = lane + k * 64;
            float x = p0[i] + p0[i + 294912] + p0[i + 2 * 294912] + p0[i + 3 * 294912];
            v[k] = x;
            sum += x;
            sq  += x * x;
        }
        #pragma unroll
        for (int msk = 32; msk >= 1; msk >>= 1) {
            sum += __shfl_xor(sum, msk);
            sq  += __shfl_xor(sq, msk);
        }
        const float mean = sum * (1.f / 576.f);
        const float var  = sq * (1.f / 576.f) - mean * mean;
        const float inv  = rsqrtf(var + 1e-5f);
        const float sc   = gamma[ch] * inv;
        const float sh   = beta[ch] - mean * sc;
        #pragma unroll
        for (int k = 0; k < 9; ++k) {
            int i = lane + k * 64;
            int b = i / 36;
            int l = i - b * 36;
            out_pose[(size_t)b * 18432 + (size_t)ch * 36 + l] = v[k] * sc + sh;
        }
        return;
    }

    // a_out blocks: one per batch b
    const int b = blockIdx.x - 128;
    for (int l = wid; l < 36; l += 4) {
        const int bl = b * 36 + l;
        float p = 0.f;
        for (int k = lane; k < KKA; k += 64) p += auf[(size_t)bl * KKA + k];
        #pragma unroll
        for (int m = 1; m <= 32; m <<= 1) p += __shfl_xor(p, m);
        if (lane == 0) atot_s[l] = p;
    }
    __syncthreads();
    for (int t = tid; t < 1152; t += 256) {
        int l = t >> 5, j = t & 31;
        int bl = b * 36 + l;
        float s = 0.f;
        #pragma unroll 9
        for (int r = 0; r < 36; ++r)
            s += arsump[((size_t)r * 32 + j) * 576 + bl];
        out_a[((size_t)b * 32 + j) * 36 + l] = s / atot_s[l];
    }
}

extern "C" void kernel_launch(void* const* d_in, const int* in_sizes, int n_in,
                              void* d_out, int out_size, void* d_ws, size_t ws_size,
                              hipStream_t stream)
{
    const float* a     = (const float*)d_in[0];
    const float* pose  = (const float*)d_in[1];
    const float* W1    = (const float*)d_in[2];
    const float* W2    = (const float*)d_in[3];
    const float* b2    = (const float*)d_in[4];
    const float* gamma = (const float*)d_in[5];
    const float* beta  = (const float*)d_in[6];
    float* out      = (float*)d_out;
    float* out_a    = out;              // [16, 32, 6, 6]
    float* out_pose = out + 18432;      // [16, 512, 6, 6]

    unsigned short* wsu = (unsigned short*)d_ws;
    unsigned short* W1b   = wsu + W1B_OFF;
    unsigned short* W2b   = wsu + W2B_OFF;
    unsigned short* pu16  = wsu + PU16_OFF;
    unsigned*       aru   = (unsigned*)(wsu + AR16_OFF);
    float* wsf    = (float*)((char*)d_ws + FREG_BYTE);
    float* auf    = wsf + AU_F;
    float* arsump = wsf + ARSUMP_F;
    float* prep   = wsf + PREP_F;

    hipLaunchKernelGGL(k_prep, dim3(1736), dim3(256), 0, stream,
                       W1, W2, a, pose, W1b, W2b, pu16, auf);
    hipLaunchKernelGGL(k_logit, dim3(18, 36), dim3(256), 0, stream,
                       W2b, pu16, b2, auf, aru, arsump);
    hipLaunchKernelGGL(k_pose, dim3(1152), dim3(256), 0, stream,
                       W1b, pu16, aru, arsump, prep);
    hipLaunchKernelGGL(k_bn, dim3(144), dim3(256), 0, stream,
                       prep, gamma, beta, arsump, auf, out_pose, out_a);
}

// Round 8
// 38.622 us; speedup vs baseline: 1.8556x; 1.8556x over previous
//
#include <hip/hip_runtime.h>

// ConvCaps: b=16, A=32, B=32, K=3, P=4, stride=2, h=w=14 -> oh=ow=6
#define AA 32
#define BB 32
#define CC 16
#define KKA 288
#define OHW 6
#define LL 36
#define NBL 576
#define HH 14
#define WWD 14

// ---- workspace layout ----
// ushort region (from byte 0):
#define W1B_OFF   0ull          // bf16 [288][512][16]  (n, ch, c)
#define W2B_OFF   2359296ull    // bf16 [288][32][16]
#define PU16_OFF  2506752ull    // bf16 [288][576][16]  (n, bl, c)
#define AR16_OFF  5160960ull    // uint [288][16jp][576bl] (bf16 j-pair packed)
// float region starts at byte 20,938,752:
#define FREG_BYTE 20938752ull
#define AU_F      0ull          // f32 [576][288]        = 165,888
#define ARSUMP_F  165888ull     // f32 [36][576][32]     = 663,552
#define INV_F     829440ull     // f32 [32][576]         =  18,432
#define PREP_F    847872ull     // f32 [4][512][576]     = 1,179,648

typedef __attribute__((ext_vector_type(8))) short bf16x8;
typedef __attribute__((ext_vector_type(4))) float f32x4;
typedef __attribute__((ext_vector_type(16))) float f32x16;

__device__ __forceinline__ unsigned cvtpk(float lo, float hi) {
    unsigned r;
    asm("v_cvt_pk_bf16_f32 %0, %1, %2" : "=v"(r) : "v"(lo), "v"(hi));
    return r;
}
__device__ __forceinline__ float blo(unsigned u) {
    return __builtin_bit_cast(float, u << 16);
}
__device__ __forceinline__ float bhi(unsigned u) {
    return __builtin_bit_cast(float, u & 0xffff0000u);
}

// ---------------------------------------------------------------------------
// Kernel 0: fused weight-cvt (blocks 0..1223) + patch gather (blocks 1224..1735)
// pu16 written in [n][bl][c] order; auf in [bl][n].   (identical to R6)
// ---------------------------------------------------------------------------
__global__ __launch_bounds__(256) void k_prep(
    const float* __restrict__ W1, const float* __restrict__ W2,
    const float* __restrict__ a, const float* __restrict__ pose,
    unsigned short* __restrict__ W1b, unsigned short* __restrict__ W2b,
    unsigned short* __restrict__ pu16, float* __restrict__ auf)
{
    __shared__ float ps[16][196];
    __shared__ float as_[196];
    const int tid = threadIdx.x;

    if (blockIdx.x < 1224) {
        size_t i = ((size_t)blockIdx.x * 256 + tid) * 8;
        const float* src;
        unsigned short* dst;
        if (i < 2359296ull) { src = W1 + i; dst = W1b + i; }
        else { src = W2 + (i - 2359296ull); dst = W2b + (i - 2359296ull); }
        float4 v0 = *reinterpret_cast<const float4*>(src);
        float4 v1 = *reinterpret_cast<const float4*>(src + 4);
        uint4 o;
        o.x = cvtpk(v0.x, v0.y);
        o.y = cvtpk(v0.z, v0.w);
        o.z = cvtpk(v1.x, v1.y);
        o.w = cvtpk(v1.z, v1.w);
        *reinterpret_cast<uint4*>(dst) = o;
        return;
    }

    const int bid = blockIdx.x - 1224;
    const int b = bid >> 5, aidx = bid & 31;

    const float* psrc = pose + ((size_t)b * 512 + (size_t)aidx * 16) * 196;
    for (int t = tid; t < 3136; t += 256) ((float*)ps)[t] = psrc[t];
    const float* asrc = a + ((size_t)b * 32 + aidx) * 196;
    if (tid < 196) as_[tid] = asrc[tid];
    __syncthreads();

    for (int t = tid; t < 1296; t += 256) {
        int quad = t & 3;
        int l = (t >> 2) % 36;
        int kk = t / 144;
        int oy = l / 6, ox = l - (l / 6) * 6;
        int ki = kk / 3, kj = kk - (kk / 3) * 3;
        int pix = (oy * 2 + ki) * 14 + ox * 2 + kj;
        uint2 v;
        v.x = cvtpk(ps[quad * 4 + 0][pix], ps[quad * 4 + 1][pix]);
        v.y = cvtpk(ps[quad * 4 + 2][pix], ps[quad * 4 + 3][pix]);
        *reinterpret_cast<uint2*>(
            pu16 + (((size_t)(kk * 32 + aidx)) * 576 + b * 36 + l) * 16 + quad * 4) = v;
    }
    for (int t = tid; t < 324; t += 256) {
        int kk = t % 9, l = t / 9;
        int oy = l / 6, ox = l - (l / 6) * 6;
        int ki = kk / 3, kj = kk - (kk / 3) * 3;
        auf[((size_t)(b * 36 + l)) * KKA + kk * 32 + aidx] =
            as_[(oy * 2 + ki) * 14 + ox * 2 + kj];
    }
}

// ---------------------------------------------------------------------------
// Kernel 1 (THE ONE CHANGE vs R6): logits via DENSE 32x32x16 MFMA
// (one per n: 32 j x 32 bl), softmax in-register (no max-sub: |logit|<=~3).
// Grid (18 bl-tiles of 32, 36 n-splits of 8); 4 waves x 2 n each.
// C layout: col bl = lane&31, row j = (i&3)+8*(i>>2)+4*kg (HW-verified).
// aru layout identical to R6; arsump written in R6's [r][bl][j] layout.
// ---------------------------------------------------------------------------
__global__ __launch_bounds__(256) void k_logit(
    const unsigned short* __restrict__ W2b, const unsigned short* __restrict__ pu16,
    const float* __restrict__ b2, const float* __restrict__ auf,
    unsigned* __restrict__ aru, float* __restrict__ arsump)
{
    __shared__ float b2_s[8][32];        // 1 KB
    __shared__ float au_s[8][32];        // 1 KB
    __shared__ float asum_s[4][64][16];  // 16 KB

    const int bl0 = blockIdx.x * 32;
    const int n0  = blockIdx.y * 8;
    const int tid = threadIdx.x;
    const int w = tid >> 6, lane = tid & 63;
    const int col = lane & 31, kg = lane >> 5;

    {
        int nl = tid >> 5, j = tid & 31;
        b2_s[nl][j] = b2[(size_t)(n0 + nl) * 32 + j];
        int nl2 = tid & 7, blr = tid >> 3;
        au_s[nl2][blr] = auf[((size_t)(bl0 + blr)) * KKA + n0 + nl2];
    }
    __syncthreads();

    float asum[16];
    #pragma unroll
    for (int i = 0; i < 16; ++i) asum[i] = 0.f;
    const f32x16 zv = {0.f,0.f,0.f,0.f,0.f,0.f,0.f,0.f,
                       0.f,0.f,0.f,0.f,0.f,0.f,0.f,0.f};

    #pragma unroll
    for (int nn = 0; nn < 2; ++nn) {
        const int nl = w * 2 + nn;
        const int n  = n0 + nl;
        uint4 a4 = *reinterpret_cast<const uint4*>(
            W2b + ((size_t)n * 32 + col) * 16 + kg * 8);
        uint4 b4 = *reinterpret_cast<const uint4*>(
            pu16 + ((size_t)n * 576 + bl0 + col) * 16 + kg * 8);
        f32x16 cd = __builtin_amdgcn_mfma_f32_32x32x16_bf16(
            __builtin_bit_cast(bf16x8, a4), __builtin_bit_cast(bf16x8, b4),
            zv, 0, 0, 0);

        float p[16];
        float s = 0.f;
        #pragma unroll
        for (int m = 0; m < 4; ++m) {
            float4 bb = *reinterpret_cast<const float4*>(&b2_s[nl][m * 8 + kg * 4]);
            p[m * 4 + 0] = __expf(cd[m * 4 + 0] + bb.x);
            p[m * 4 + 1] = __expf(cd[m * 4 + 1] + bb.y);
            p[m * 4 + 2] = __expf(cd[m * 4 + 2] + bb.z);
            p[m * 4 + 3] = __expf(cd[m * 4 + 3] + bb.w);
            s += p[m*4+0] + p[m*4+1] + p[m*4+2] + p[m*4+3];
        }
        s += __shfl_xor(s, 32);                  // other kg half -> all 32 j
        const float scale = au_s[nl][col] / s;   // a_u * softmax
        #pragma unroll
        for (int i = 0; i < 16; ++i) { p[i] *= scale; asum[i] += p[i]; }

        // pack (j, j+1) pairs -> aru[n][jp][bl]  (same layout as R6)
        #pragma unroll
        for (int t = 0; t < 8; ++t) {
            int jp = (t & 1) + 4 * (t >> 1) + 2 * kg;
            aru[((size_t)n * 16 + jp) * 576 + bl0 + col] =
                cvtpk(p[2 * t], p[2 * t + 1]);
        }
    }
    #pragma unroll
    for (int i = 0; i < 16; ++i) asum_s[w][lane][i] = asum[i];
    __syncthreads();
    // reduce 4 waves -> arsump[ns][bl][j]  (R6's coalesced layout)
    #pragma unroll
    for (int k = 0; k < 4; ++k) {
        int idx = tid + k * 256;
        int dd = idx >> 5, j = idx & 31;
        int kg2 = (j >> 2) & 1;
        int i2  = (j & 3) + 4 * (j >> 3);
        float s = asum_s[0][dd + 32 * kg2][i2] + asum_s[1][dd + 32 * kg2][i2]
                + asum_s[2][dd + 32 * kg2][i2] + asum_s[3][dd + 32 * kg2][i2];
        arsump[(size_t)blockIdx.y * 18432 + ((size_t)(bl0 + dd)) * 32 + j] = s;
    }
}

// ---------------------------------------------------------------------------
// Kernel 2: finish routing — inv[j][bl] = 1/arsum; a_out = arsum/au_tot.
// (identical to R6, 36 partial rows instead of 18)
// ---------------------------------------------------------------------------
__global__ __launch_bounds__(256) void k_finish(
    const float* __restrict__ arsump, const float* __restrict__ auf,
    float* __restrict__ invarsum, float* __restrict__ out_a)
{
    const int tid = threadIdx.x;
    const int wid = tid >> 6, lane = tid & 63;
    const int bl = blockIdx.x * 4 + wid;
    const int j = lane & 31, h = lane >> 5;

    float s = 0.f;
    #pragma unroll
    for (int k = 0; k < 18; ++k) {
        int r = h * 18 + k;
        s += arsump[(size_t)r * 18432 + (size_t)bl * 32 + j];
    }
    s += __shfl_xor(s, 32);

    float at = 0.f;
    #pragma unroll
    for (int k = 0; k < 5; ++k) {
        int n = k * 64 + lane;
        if (n < KKA) at += auf[(size_t)bl * KKA + n];
    }
    #pragma unroll
    for (int m = 1; m <= 32; m <<= 1) at += __shfl_xor(at, m);

    if (lane < 32) {
        invarsum[(size_t)j * 576 + bl] = 1.0f / s;
        int b = bl / 36, l = bl - (bl / 36) * 36;
        out_a[((size_t)b * 32 + j) * 36 + l] = s / at;
    }
}

// ---------------------------------------------------------------------------
// Kernel 3: pose contraction via 32x32x16 MFMA, all-global operands.
// Grid 1152 = 18 bl-tiles(32) x 16 jp x 4 n-quarters(72), XCD-swizzled.
// (identical to R6)
// ---------------------------------------------------------------------------
__global__ __launch_bounds__(256) void k_pose(
    const unsigned short* __restrict__ W1b, const unsigned short* __restrict__ pu16,
    const unsigned* __restrict__ aru, const float* __restrict__ invarsum,
    float* __restrict__ prep)
{
    __shared__ float red_s[3][16][64];   // 12 KB

    const int bid = blockIdx.x;
    const int wg  = (bid & 7) * 144 + (bid >> 3);   // bijective (1152 % 8 == 0)
    const int q   = wg / 288;
    const int rem = wg - q * 288;
    const int jp  = rem / 18;
    const int bl0 = (rem - jp * 18) * 32;

    const int tid = threadIdx.x;
    const int w = tid >> 6, lane = tid & 63;
    const int col = lane & 31, kg = lane >> 5;

    const unsigned short* wp = W1b + ((size_t)(jp * 32 + col)) * 16 + kg * 8;
    const unsigned short* pp = pu16 + ((size_t)(bl0 + col)) * 16 + kg * 8;
    const unsigned* ap = aru + (size_t)jp * 576 + bl0 + col;
    const int n0 = q * 72 + w * 18;

    float acc[16];
    #pragma unroll
    for (int i = 0; i < 16; ++i) acc[i] = 0.f;
    f32x16 zv = {0.f,0.f,0.f,0.f,0.f,0.f,0.f,0.f,0.f,0.f,0.f,0.f,0.f,0.f,0.f,0.f};

    #pragma unroll 6
    for (int i = 0; i < 18; ++i) {
        const size_t n = (size_t)(n0 + i);
        uint4 a4 = *reinterpret_cast<const uint4*>(wp + n * 8192);   // 512*16
        uint4 b4 = *reinterpret_cast<const uint4*>(pp + n * 9216);   // 576*16
        unsigned av = ap[n * 9216];                                  // 16*576
        f32x16 cd = __builtin_amdgcn_mfma_f32_32x32x16_bf16(
            __builtin_bit_cast(bf16x8, a4), __builtin_bit_cast(bf16x8, b4),
            zv, 0, 0, 0);
        float slo = blo(av), shi = bhi(av);
        #pragma unroll
        for (int r = 0; r < 8; ++r)  acc[r] = fmaf(cd[r], slo, acc[r]);
        #pragma unroll
        for (int r = 8; r < 16; ++r) acc[r] = fmaf(cd[r], shi, acc[r]);
    }

    if (w > 0) {
        #pragma unroll
        for (int i = 0; i < 16; ++i) red_s[w - 1][i][lane] = acc[i];
    }
    __syncthreads();
    if (w == 0) {
        const float ilo = invarsum[(size_t)(jp * 2) * 576 + bl0 + col];
        const float ihi = invarsum[(size_t)(jp * 2 + 1) * 576 + bl0 + col];
        #pragma unroll
        for (int i = 0; i < 16; ++i) {
            float v = acc[i] + red_s[0][i][lane] + red_s[1][i][lane] + red_s[2][i][lane];
            int r = (i & 3) + 8 * (i >> 2) + 4 * kg;       // C row
            float vv = v * (i < 8 ? ilo : ihi);
            prep[((size_t)q * 512 + jp * 32 + r) * NBL + bl0 + col] = vv;
        }
    }
}

// ---------------------------------------------------------------------------
// Kernel 4: BatchNorm (batch stats, biased var) + layout to [b, 512, 6, 6].
// Sums the 4 n-quarter planes of prep.  (identical to R6)
// ---------------------------------------------------------------------------
__global__ __launch_bounds__(256) void k_bn(
    const float* __restrict__ prep, const float* __restrict__ gamma,
    const float* __restrict__ beta, float* __restrict__ out_pose)
{
    const int tid = threadIdx.x;
    const int wid = tid >> 6, lane = tid & 63;
    const int ch  = blockIdx.x * 4 + wid;
    const float* p0 = prep + (size_t)ch * NBL;

    float sum = 0.f, sq = 0.f;
    float v[9];
    #pragma unroll
    for (int k = 0; k < 9; ++k) {
        int i = lane + k * 64;
        float x = p0[i] + p0[i + 294912] + p0[i + 2 * 294912] + p0[i + 3 * 294912];
        v[k] = x;
        sum += x;
        sq  += x * x;
    }
    #pragma unroll
    for (int msk = 32; msk >= 1; msk >>= 1) {
        sum += __shfl_xor(sum, msk);
        sq  += __shfl_xor(sq, msk);
    }
    const float mean = sum * (1.f / 576.f);
    const float var  = sq * (1.f / 576.f) - mean * mean;
    const float inv  = rsqrtf(var + 1e-5f);
    const float sc   = gamma[ch] * inv;
    const float sh   = beta[ch] - mean * sc;
    #pragma unroll
    for (int k = 0; k < 9; ++k) {
        int i = lane + k * 64;
        int b = i / 36;
        int l = i - b * 36;
        out_pose[(size_t)b * 18432 + (size_t)ch * 36 + l] = v[k] * sc + sh;
    }
}

extern "C" void kernel_launch(void* const* d_in, const int* in_sizes, int n_in,
                              void* d_out, int out_size, void* d_ws, size_t ws_size,
                              hipStream_t stream)
{
    const float* a     = (const float*)d_in[0];
    const float* pose  = (const float*)d_in[1];
    const float* W1    = (const float*)d_in[2];
    const float* W2    = (const float*)d_in[3];
    const float* b2    = (const float*)d_in[4];
    const float* gamma = (const float*)d_in[5];
    const float* beta  = (const float*)d_in[6];
    float* out      = (float*)d_out;
    float* out_a    = out;              // [16, 32, 6, 6]
    float* out_pose = out + 18432;      // [16, 512, 6, 6]

    unsigned short* wsu = (unsigned short*)d_ws;
    unsigned short* W1b   = wsu + W1B_OFF;
    unsigned short* W2b   = wsu + W2B_OFF;
    unsigned short* pu16  = wsu + PU16_OFF;
    unsigned*       aru   = (unsigned*)(wsu + AR16_OFF);
    float* wsf    = (float*)((char*)d_ws + FREG_BYTE);
    float* auf    = wsf + AU_F;
    float* arsump = wsf + ARSUMP_F;
    float* invv   = wsf + INV_F;
    float* prep   = wsf + PREP_F;

    hipLaunchKernelGGL(k_prep, dim3(1736), dim3(256), 0, stream,
                       W1, W2, a, pose, W1b, W2b, pu16, auf);
    hipLaunchKernelGGL(k_logit, dim3(18, 36), dim3(256), 0, stream,
                       W2b, pu16, b2, auf, aru, arsump);
    hipLaunchKernelGGL(k_finish, dim3(144), dim3(256), 0, stream,
                       arsump, auf, invv, out_a);
    hipLaunchKernelGGL(k_pose, dim3(1152), dim3(256), 0, stream,
                       W1b, pu16, aru, invv, prep);
    hipLaunchKernelGGL(k_bn, dim3(128), dim3(256), 0, stream,
                       prep, gamma, beta, out_pose);
}